// Round 1
// baseline (49.168 us; speedup 1.0000x reference)
//
#include <hip/hip_runtime.h>

// TreeLoss: 2-level hierarchical softmax loss.
// Structure (from _build_state_space): 56 children (nodes 0..55), 8 parents
// (nodes 56..63), parent(c) = 56 + c/7. State space rows:
//   row 0: zeros -> contributes exp(0)=1 to z
//   per parent: one parent-only row, then 7 (parent,child) rows.
// z(b)       = 1 + sum_p e^{x_p} + sum_c e^{x_c} * e^{x_parent(c)}
// marginal(b)= e^{x_g + x_parent(g)}   (only one state row contains child g)
// loss(b)    = log z - (x_g + x_parent(g));  output = mean over batch.

__global__ void __launch_bounds__(256) tree_loss_partial(
    const float* __restrict__ pred,   // [rows, 64]
    const int*   __restrict__ gt,     // [rows], values 0..55
    float*       __restrict__ partial,// [gridDim.x]
    int rows)
{
    const int lane        = threadIdx.x & 63;
    const int waveInBlock = threadIdx.x >> 6;
    const int wavesPerBlk = blockDim.x >> 6;
    const int gwave       = blockIdx.x * wavesPerBlk + waveInBlock;
    const int nwaves      = gridDim.x * wavesPerBlk;

    // Per-lane parent-lane index (children: 56 + lane/7; parents: self).
    const int plane = (lane < 56) ? (56 + lane / 7) : lane;

    float acc = 0.0f;
    for (int row = gwave; row < rows; row += nwaves) {
        // Coalesced: wave reads one contiguous 256B row.
        float x = pred[row * 64 + lane];
        float e = __expf(x);
        float ep = __shfl(e, plane);            // parent's exp (self for parents)
        float v = (lane < 56) ? e * ep : e;     // child: e_c*e_p ; parent: e_p
        // Wave sum of v across all 64 lanes (butterfly).
        float s = v;
        #pragma unroll
        for (int off = 32; off; off >>= 1) s += __shfl_xor(s, off);
        // Ground-truth term (g is wave-uniform; shfl broadcasts).
        int g = gt[row];                         // same addr all lanes -> broadcast
        float xg = __shfl(x, g);
        float xp = __shfl(x, 56 + g / 7);
        // All lanes hold identical s -> identical loss; counted once at writeback.
        acc += __logf(1.0f + s) - (xg + xp);
    }

    __shared__ float lsum[8];
    if (lane == 0) lsum[waveInBlock] = acc;      // every lane's acc is identical
    __syncthreads();
    if (threadIdx.x == 0) {
        float b = 0.0f;
        for (int w = 0; w < wavesPerBlk; ++w) b += lsum[w];
        partial[blockIdx.x] = b;
    }
}

__global__ void __launch_bounds__(256) tree_loss_final(
    const float* __restrict__ partial, int n,
    float* __restrict__ out, float inv)
{
    float s = 0.0f;
    for (int i = threadIdx.x; i < n; i += blockDim.x) s += partial[i];
    #pragma unroll
    for (int off = 32; off; off >>= 1) s += __shfl_xor(s, off);
    __shared__ float w[4];
    const int lane = threadIdx.x & 63;
    const int wv   = threadIdx.x >> 6;
    if (lane == 0) w[wv] = s;
    __syncthreads();
    if (threadIdx.x == 0) out[0] = (w[0] + w[1] + w[2] + w[3]) * inv;
}

extern "C" void kernel_launch(void* const* d_in, const int* in_sizes, int n_in,
                              void* d_out, int out_size, void* d_ws, size_t ws_size,
                              hipStream_t stream) {
    const float* pred = (const float*)d_in[0];   // [B,64] fp32
    const int*   gt   = (const int*)d_in[1];     // [B] int32
    // d_in[2] (state_space) unused: tree structure is fixed by the problem.
    float* out     = (float*)d_out;
    float* partial = (float*)d_ws;
    const int rows = in_sizes[1];                // BATCH = 262144

    int blocks = 1024;                           // 4096 waves, 64 rows/wave
    size_t need = (size_t)blocks * sizeof(float);
    if (ws_size < need) blocks = (int)(ws_size / sizeof(float));
    if (blocks < 1) blocks = 1;

    tree_loss_partial<<<blocks, 256, 0, stream>>>(pred, gt, partial, rows);
    tree_loss_final<<<1, 256, 0, stream>>>(partial, blocks, out, 1.0f / (float)rows);
}

// Round 3
// 22.724 us; speedup vs baseline: 2.1637x; 2.1637x over previous
//
#include <hip/hip_runtime.h>

// TreeLoss: 2-level hierarchical softmax loss.
// z(b)       = 1 + sum_p e^{x_p} * (1 + sum_{c in p} e^{x_c})
// marginal(b)= e^{x_g} * e^{x_parent(g)}
// loss(b)    = log(z / marginal); output = mean over batch.
//
// Design (R3 = R2 with staging-loop fix): thread-per-row. Each block stages
// 256 rows (64KB) of exp'd values into LDS with +1 padding (row stride 65
// floats -> (t+j)%32 bank pattern, 2 lanes/bank = free on CDNA4), then each
// thread reduces its own row with zero cross-lane ops.
// R2 bug: staging loop ran 4 iters (1024 float4) but tile is 4096 float4 ->
// rows 64..255 read uninitialized LDS -> NaN. Now 16 iters.

#define ROWS_PER_BLOCK 256
#define ROW_PAD 65

__global__ void __launch_bounds__(256) tree_loss_partial(
    const float* __restrict__ pred,   // [rows, 64]
    const int*   __restrict__ gt,     // [rows], values 0..55
    float*       __restrict__ partial,// [gridDim.x]
    int rows)
{
    __shared__ float lds[ROWS_PER_BLOCK * ROW_PAD];  // 66560 B
    __shared__ float wsum[4];

    const int t = threadIdx.x;
    const int rowBase = blockIdx.x * ROWS_PER_BLOCK;

    // ---- Stage: coalesced float4 loads, exp applied in-flight ----
    // Block tile = 256 rows x 16 float4 = 4096 float4s; 16 per thread.
    const float4* p4 = (const float4*)pred + (size_t)rowBase * 16;
    #pragma unroll
    for (int i = 0; i < 16; ++i) {
        int f   = i * 256 + t;          // float4 index within tile, 0..4095
        int row = f >> 4;               // 0..255
        int col = (f & 15) << 2;        // 0..60
        if (rowBase + row < rows) {
            float4 v = p4[f];
            float* dst = &lds[row * ROW_PAD + col];
            dst[0] = __expf(v.x);
            dst[1] = __expf(v.y);
            dst[2] = __expf(v.z);
            dst[3] = __expf(v.w);
        }
    }
    __syncthreads();

    // ---- Compute: one row per thread, no cross-lane ops ----
    float loss = 0.0f;
    const int rowg = rowBase + t;
    if (rowg < rows) {
        const float* e = &lds[t * ROW_PAD];
        float z = 1.0f;
        #pragma unroll
        for (int p = 0; p < 8; ++p) {
            float s = 1.0f;
            #pragma unroll
            for (int c = 0; c < 7; ++c) s += e[p * 7 + c];
            z += e[56 + p] * s;
        }
        int g = gt[rowg];                       // coalesced
        float m = e[g] * e[56 + g / 7];         // marginal
        loss = __logf(z / m);
    }

    // ---- Block reduction ----
    #pragma unroll
    for (int off = 32; off; off >>= 1) loss += __shfl_xor(loss, off);
    const int lane = t & 63, wv = t >> 6;
    if (lane == 0) wsum[wv] = loss;
    __syncthreads();
    if (t == 0) partial[blockIdx.x] = wsum[0] + wsum[1] + wsum[2] + wsum[3];
}

__global__ void __launch_bounds__(256) tree_loss_final(
    const float* __restrict__ partial, int n,
    float* __restrict__ out, float inv)
{
    float s = 0.0f;
    for (int i = threadIdx.x; i < n; i += blockDim.x) s += partial[i];
    #pragma unroll
    for (int off = 32; off; off >>= 1) s += __shfl_xor(s, off);
    __shared__ float w[4];
    const int lane = threadIdx.x & 63;
    const int wv   = threadIdx.x >> 6;
    if (lane == 0) w[wv] = s;
    __syncthreads();
    if (threadIdx.x == 0) out[0] = (w[0] + w[1] + w[2] + w[3]) * inv;
}

extern "C" void kernel_launch(void* const* d_in, const int* in_sizes, int n_in,
                              void* d_out, int out_size, void* d_ws, size_t ws_size,
                              hipStream_t stream) {
    const float* pred = (const float*)d_in[0];   // [B,64] fp32
    const int*   gt   = (const int*)d_in[1];     // [B] int32
    float* out     = (float*)d_out;
    float* partial = (float*)d_ws;
    const int rows = in_sizes[1];                // BATCH = 262144

    int blocks = (rows + ROWS_PER_BLOCK - 1) / ROWS_PER_BLOCK;  // 1024
    tree_loss_partial<<<blocks, 256, 0, stream>>>(pred, gt, partial, rows);
    tree_loss_final<<<1, 256, 0, stream>>>(partial, blocks, out, 1.0f / (float)rows);
}